// Round 4
// baseline (1039.945 us; speedup 1.0000x reference)
//
#include <hip/hip_runtime.h>

// ---------------------------------------------------------------------------
// PointNet++ set-abstraction block on MI355X.
// B=8, N=4096, K=32, D=64; out [B,N,128] fp32.
//  - layer0 linear decomposition: h0_pre = R[j] - Q[n]
//  - BN training-mode stats via per-block partials + finalize kernels
//  - layers 1/2 as fp16 MFMA (16x16x32) with fp32 accum
//  - max over K commutes with monotone BN affine: store max&min of h2 only
//  - kNN: R1-proven wave insertion sort + provably-safe lane-min-max
//    prefilter (tau = max_lane(min_c d) => >=64 candidates <= tau => top-32
//    subset of filter); batch staged once in LDS; distances cached in regs.
// ---------------------------------------------------------------------------

using half8  = __attribute__((ext_vector_type(8))) _Float16;
using floatx4 = __attribute__((ext_vector_type(4))) float;

#define NB 8
#define NP 4096
#define NQ (NB*NP)          // 32768 points / queries
#define CNT_INV (1.0f/1048576.0f)   // 1/(B*N*K), exact power of two

// ---- workspace layout (bytes) ----
#define OFF_XYZ4  0ull
#define OFF_Q     (OFF_XYZ4 + (size_t)NQ*4*4)       // xyz4: x,y,z,|x|^2
#define OFF_R     (OFF_Q    + (size_t)NQ*64*4)
#define OFF_IDX   (OFF_R    + (size_t)NQ*64*4)
#define OFF_W1H   (OFF_IDX  + (size_t)NQ*32*4)
#define OFF_W2H   (OFF_W1H  + 4096*2)
#define OFF_P0    (OFF_W2H  + 8192*2)
#define OFF_P1    (OFF_P0   + (size_t)1024*128*4)
#define OFF_P2    (OFF_P1   + (size_t)1024*128*4)
#define OFF_PAR   (OFF_P2   + (size_t)1024*256*4)
#define OFF_MMAX  (OFF_PAR  + 512*4)
#define OFF_MMIN  (OFF_MMAX + (size_t)NQ*128*4)

// ---------------------------------------------------------------------------
// K0: per-point prep: xyz4=(x,y,z,sq), Q = W0_xyz@xyz, R = Q + W0_pts@pts + b0
// ---------------------------------------------------------------------------
__global__ __launch_bounds__(256) void k_prep(
    const float* __restrict__ xyz, const float* __restrict__ points,
    const float* __restrict__ W0, const float* __restrict__ b0,
    float* __restrict__ xyz4, float* __restrict__ Q, float* __restrict__ R) {
  __shared__ float w0s[64*67];
  for (int i = threadIdx.x; i < 64*67; i += 256) w0s[i] = W0[i];
  __syncthreads();
  int p = blockIdx.x*4 + (threadIdx.x >> 6);
  int o = threadIdx.x & 63;
  float x = xyz[p*3+0], y = xyz[p*3+1], z = xyz[p*3+2];
  const float* wr = w0s + o*67;
  float q = wr[0]*x + wr[1]*y + wr[2]*z;
  float r = b0[o] + q;
  const float* pp = points + (size_t)p*64;
  #pragma unroll 16
  for (int c = 0; c < 64; ++c) r = fmaf(wr[3+c], pp[c], r);
  Q[(size_t)p*64 + o] = q;
  R[(size_t)p*64 + o] = r;
  if (o == 0) {
    float sq = fmaf(x,x, fmaf(y,y, z*z));
    xyz4[p*4+0]=x; xyz4[p*4+1]=y; xyz4[p*4+2]=z; xyz4[p*4+3]=sq;
  }
}

// ---------------------------------------------------------------------------
// K0b: cast W1 (64x64), W2 (128x64) to fp16 row-major [o][c]
// ---------------------------------------------------------------------------
__global__ __launch_bounds__(256) void k_cast(
    const float* __restrict__ W1, const float* __restrict__ W2,
    _Float16* __restrict__ W1h, _Float16* __restrict__ W2h) {
  int t = blockIdx.x*256 + threadIdx.x;
  if (t < 4096) W1h[t] = (_Float16)W1[t];
  if (t < 8192) W2h[t] = (_Float16)W2[t];
}

// ---------------------------------------------------------------------------
// K1: exact kNN — R1-proven selection core + provably-safe prefilter.
// Block stages its batch's 4096 float4 in LDS once; 64 queries/block,
// 16/wave. Per query: pass1 computes all 64 per-lane distances into regs
// (dv[64]) and the per-lane min; tau = wave-max of lane mins (>=64 cands
// <= tau, so top-32 subset of {d <= tau}); pass2 = R1 insertion sort over
// filtered candidates only (~300 of 4096 -> ~105 serialized inserts).
// ---------------------------------------------------------------------------
__device__ __forceinline__ unsigned fmap(float f) {
  unsigned u = __float_as_uint(f);
  return u ^ ((unsigned)((int)u >> 31) | 0x80000000u);
}

__global__ __launch_bounds__(256) void k_knn(
    const float* __restrict__ xyz4, int* __restrict__ idxb) {
  __shared__ float4 tile[NP];          // 64 KB: whole batch
  const int lane = threadIdx.x & 63;
  const int w = threadIdx.x >> 6;
  const int q0 = blockIdx.x * 64;      // 64 consecutive queries per block
  const int b  = q0 >> 12;             // uniform across block (64 | 4096)
  const float4* xb = (const float4*)xyz4 + (size_t)b * NP;
  for (int i = threadIdx.x; i < NP; i += 256) tile[i] = xb[i];
  __syncthreads();

  const int qbase = q0 + w*16;
  #pragma unroll 1
  for (int qi = 0; qi < 16; ++qi) {
    const int qid = qbase + qi;
    const float4 qv = tile[qid & (NP-1)];
    int* op = idxb + (size_t)qid * 32;

    // ---- pass 1: distances into registers + per-lane min ----
    float dv[64];
    float mn = __uint_as_float(0x7F800000u);
    #pragma unroll
    for (int c = 0; c < 64; ++c) {
      float4 cd = tile[c*64 + lane];
      float dot = fmaf(qv.x, cd.x, fmaf(qv.y, cd.y, qv.z*cd.z));
      float d   = fmaf(-2.0f, dot, qv.w + cd.w);
      dv[c] = d;
      mn = fminf(mn, d);
    }
    // safe threshold: tau = max over lanes of per-lane min
    float tau = mn;
    tau = fmaxf(tau, __shfl_xor(tau, 1));
    tau = fmaxf(tau, __shfl_xor(tau, 2));
    tau = fmaxf(tau, __shfl_xor(tau, 4));
    tau = fmaxf(tau, __shfl_xor(tau, 8));
    tau = fmaxf(tau, __shfl_xor(tau, 16));
    tau = fmaxf(tau, __shfl_xor(tau, 32));

    // ---- pass 2: R1-verbatim insertion sort, filtered to d <= tau ----
    unsigned ku = 0xFFFFFFFFu;   // sorted keys, lanes 0..31 ascending
    int jv = 0;
    unsigned thr = 0xFFFFFFFFu;  // current 32nd-smallest key (wave uniform)
    #pragma unroll
    for (int c = 0; c < 64; ++c) {
      unsigned u = fmap(dv[c]);
      int j = c*64 + lane;
      unsigned long long ball = __ballot(dv[c] <= tau && u < thr);
      while (ball) {
        int src = __ffsll(ball) - 1;
        ball &= ball - 1;
        unsigned cu = __shfl(u, src);
        int cj = __shfl(j, src);
        if (cu < thr) {   // recheck: thr may have tightened
          unsigned long long m = __ballot(lane < 32 && ku < cu);
          int pos = __popcll(m);
          unsigned ku_up = __shfl_up(ku, 1);
          int jv_up = __shfl_up(jv, 1);
          if (lane < 32) {
            if (lane > pos)      { ku = ku_up; jv = jv_up; }
            else if (lane == pos){ ku = cu;    jv = cj;    }
          }
          thr = __shfl(ku, 31);
        }
      }
    }
    if (lane < 32) op[lane] = jv;
  }
}

// ---------------------------------------------------------------------------
// K2: stats of h0_pre = R[j] - Q[n].  1024 blocks x 32 queries.
// ---------------------------------------------------------------------------
__global__ __launch_bounds__(256) void k_stats0(
    const float* __restrict__ R, const float* __restrict__ Q,
    const int* __restrict__ idxb, float* __restrict__ p0) {
  int o = threadIdx.x & 63, wg = threadIdx.x >> 6;
  float s = 0.f, ss = 0.f;
  for (int qi = 0; qi < 8; ++qi) {
    int qid = blockIdx.x*32 + wg*8 + qi;
    const float* Rb = R + (size_t)(qid & ~4095)*64;
    float qv = Q[(size_t)qid*64 + o];
    const int* ix = idxb + (size_t)qid*32;
    #pragma unroll 8
    for (int k = 0; k < 32; ++k) {
      float v = Rb[(size_t)ix[k]*64 + o] - qv;
      s += v; ss = fmaf(v, v, ss);
    }
  }
  __shared__ float red[512];
  red[threadIdx.x] = s; red[256 + threadIdx.x] = ss;
  __syncthreads();
  if (threadIdx.x < 64) {
    float S  = red[o] + red[64+o] + red[128+o] + red[192+o];
    float SS = red[256+o] + red[320+o] + red[384+o] + red[448+o];
    p0[blockIdx.x*128 + o]      = S;
    p0[blockIdx.x*128 + 64 + o] = SS;
  }
}

// ---------------------------------------------------------------------------
// K3: finalize BN stats -> affine params (scale, shift) at par[poff..]
// ---------------------------------------------------------------------------
__global__ void k_fin(const float* __restrict__ part, int C,
                      const float* __restrict__ g, const float* __restrict__ beta,
                      float* __restrict__ par, int poff) {
  int o = threadIdx.x;
  float S = 0.f, SS = 0.f;
  for (int s = 0; s < 1024; ++s) {
    S  += part[s*2*C + o];
    SS += part[s*2*C + C + o];
  }
  float mu  = S * CNT_INV;
  float var = SS * CNT_INV - mu*mu;
  float sc  = g[o] * rsqrtf(var + 1e-5f);
  par[poff + o]     = sc;
  par[poff + C + o] = beta[o] - mu*sc;
}

// ---------------------------------------------------------------------------
// K4: layer1 via fp16 MFMA; emit stats1 partials.
// ---------------------------------------------------------------------------
__global__ __launch_bounds__(256) void k_l1(
    const float* __restrict__ R, const float* __restrict__ Q,
    const int* __restrict__ idxb, const _Float16* __restrict__ W1h,
    const float* __restrict__ b1, const float* __restrict__ par,
    float* __restrict__ p1) {
  __shared__ __align__(16) _Float16 x1[128*72];
  int o = threadIdx.x & 63, wg = threadIdx.x >> 6;
  int m16 = o & 15, quad = o >> 4;
  float sc0 = par[o], sh0 = par[64 + o];
  int col = wg*16 + m16;
  half8 bf0 = *(const half8*)(W1h + col*64 + quad*8);
  half8 bf1 = *(const half8*)(W1h + col*64 + 32 + quad*8);
  float b1c = b1[col];
  float s = 0.f, ss = 0.f;

  for (int gi = 0; gi < 8; ++gi) {
    int q0 = (blockIdx.x*8 + gi) * 4;
    {
      int qid = q0 + wg;
      const float* Rb = R + (size_t)(qid & ~4095)*64;
      float qv = Q[(size_t)qid*64 + o];
      const int* ix = idxb + (size_t)qid*32;
      #pragma unroll 4
      for (int r = 0; r < 32; ++r) {
        float v = fmaf(Rb[(size_t)ix[r]*64 + o] - qv, sc0, sh0);
        x1[(wg*32 + r)*72 + o] = (_Float16)fmaxf(v, 0.f);
      }
    }
    __syncthreads();
    #pragma unroll
    for (int rt = 0; rt < 8; ++rt) {
      const _Float16* ap = x1 + (rt*16 + m16)*72 + quad*8;
      half8 a0 = *(const half8*)(ap);
      half8 a1 = *(const half8*)(ap + 32);
      floatx4 acc = {0.f,0.f,0.f,0.f};
      acc = __builtin_amdgcn_mfma_f32_16x16x32_f16(a0, bf0, acc, 0,0,0);
      acc = __builtin_amdgcn_mfma_f32_16x16x32_f16(a1, bf1, acc, 0,0,0);
      #pragma unroll
      for (int rg = 0; rg < 4; ++rg) {
        float h = acc[rg] + b1c;
        s += h; ss = fmaf(h, h, ss);
      }
    }
    __syncthreads();
  }
  s  += __shfl_xor(s, 16);  s  += __shfl_xor(s, 32);
  ss += __shfl_xor(ss, 16); ss += __shfl_xor(ss, 32);
  if (quad == 0) {
    p1[blockIdx.x*128 + col]      = s;
    p1[blockIdx.x*128 + 64 + col] = ss;
  }
}

// ---------------------------------------------------------------------------
// K6: layer1 (recompute) -> bn1+relu -> layer2 MFMA -> stats2 + max/min
// ---------------------------------------------------------------------------
__global__ __launch_bounds__(256) void k_l2(
    const float* __restrict__ R, const float* __restrict__ Q,
    const int* __restrict__ idxb, const _Float16* __restrict__ W1h,
    const _Float16* __restrict__ W2h, const float* __restrict__ b1,
    const float* __restrict__ b2, const float* __restrict__ par,
    float* __restrict__ p2, float* __restrict__ Mmax, float* __restrict__ Mmin) {
  __shared__ __align__(16) _Float16 x1[128*72];
  __shared__ __align__(16) _Float16 x2[128*72];
  int o = threadIdx.x & 63, wg = threadIdx.x >> 6;
  int m16 = o & 15, quad = o >> 4;
  float sc0 = par[o], sh0 = par[64 + o];
  int col1 = wg*16 + m16;
  float sc1 = par[128 + col1], sh1 = par[192 + col1];
  half8 b1f0 = *(const half8*)(W1h + col1*64 + quad*8);
  half8 b1f1 = *(const half8*)(W1h + col1*64 + 32 + quad*8);
  float b1c = b1[col1];
  int colA = wg*16 + m16, colB = 64 + wg*16 + m16;
  half8 b2A0 = *(const half8*)(W2h + colA*64 + quad*8);
  half8 b2A1 = *(const half8*)(W2h + colA*64 + 32 + quad*8);
  half8 b2B0 = *(const half8*)(W2h + colB*64 + quad*8);
  half8 b2B1 = *(const half8*)(W2h + colB*64 + 32 + quad*8);
  float b2a = b2[colA], b2b = b2[colB];
  float sA=0.f, ssA=0.f, sB=0.f, ssB=0.f;

  for (int gi = 0; gi < 8; ++gi) {
    int q0 = (blockIdx.x*8 + gi) * 4;
    {
      int qid = q0 + wg;
      const float* Rb = R + (size_t)(qid & ~4095)*64;
      float qv = Q[(size_t)qid*64 + o];
      const int* ix = idxb + (size_t)qid*32;
      #pragma unroll 4
      for (int r = 0; r < 32; ++r) {
        float v = fmaf(Rb[(size_t)ix[r]*64 + o] - qv, sc0, sh0);
        x1[(wg*32 + r)*72 + o] = (_Float16)fmaxf(v, 0.f);
      }
    }
    __syncthreads();
    #pragma unroll
    for (int rt = 0; rt < 8; ++rt) {
      const _Float16* ap = x1 + (rt*16 + m16)*72 + quad*8;
      half8 a0 = *(const half8*)(ap);
      half8 a1 = *(const half8*)(ap + 32);
      floatx4 acc = {0.f,0.f,0.f,0.f};
      acc = __builtin_amdgcn_mfma_f32_16x16x32_f16(a0, b1f0, acc, 0,0,0);
      acc = __builtin_amdgcn_mfma_f32_16x16x32_f16(a1, b1f1, acc, 0,0,0);
      #pragma unroll
      for (int rg = 0; rg < 4; ++rg) {
        float h = acc[rg] + b1c;
        float v = fmaxf(fmaf(h, sc1, sh1), 0.f);
        x2[(rt*16 + quad*4 + rg)*72 + col1] = (_Float16)v;
      }
    }
    __syncthreads();
    float mxA=0.f, mnA=0.f, mxB=0.f, mnB=0.f;
    #pragma unroll
    for (int rt = 0; rt < 8; ++rt) {
      const _Float16* ap = x2 + (rt*16 + m16)*72 + quad*8;
      half8 a0 = *(const half8*)(ap);
      half8 a1 = *(const half8*)(ap + 32);
      floatx4 accA = {0.f,0.f,0.f,0.f}, accB = {0.f,0.f,0.f,0.f};
      accA = __builtin_amdgcn_mfma_f32_16x16x32_f16(a0, b2A0, accA, 0,0,0);
      accA = __builtin_amdgcn_mfma_f32_16x16x32_f16(a1, b2A1, accA, 0,0,0);
      accB = __builtin_amdgcn_mfma_f32_16x16x32_f16(a0, b2B0, accB, 0,0,0);
      accB = __builtin_amdgcn_mfma_f32_16x16x32_f16(a1, b2B1, accB, 0,0,0);
      float hA0 = accA[0]+b2a, hA1 = accA[1]+b2a, hA2 = accA[2]+b2a, hA3 = accA[3]+b2a;
      float hB0 = accB[0]+b2b, hB1 = accB[1]+b2b, hB2 = accB[2]+b2b, hB3 = accB[3]+b2b;
      sA += hA0+hA1+hA2+hA3;
      ssA = fmaf(hA0,hA0, fmaf(hA1,hA1, fmaf(hA2,hA2, fmaf(hA3,hA3, ssA))));
      sB += hB0+hB1+hB2+hB3;
      ssB = fmaf(hB0,hB0, fmaf(hB1,hB1, fmaf(hB2,hB2, fmaf(hB3,hB3, ssB))));
      float m4A = fmaxf(fmaxf(hA0,hA1), fmaxf(hA2,hA3));
      float n4A = fminf(fminf(hA0,hA1), fminf(hA2,hA3));
      float m4B = fmaxf(fmaxf(hB0,hB1), fmaxf(hB2,hB3));
      float n4B = fminf(fminf(hB0,hB1), fminf(hB2,hB3));
      if ((rt & 1) == 0) { mxA=m4A; mnA=n4A; mxB=m4B; mnB=n4B; }
      else {
        mxA=fmaxf(mxA,m4A); mnA=fminf(mnA,n4A);
        mxB=fmaxf(mxB,m4B); mnB=fminf(mnB,n4B);
        mxA=fmaxf(mxA,__shfl_xor(mxA,16)); mxA=fmaxf(mxA,__shfl_xor(mxA,32));
        mnA=fminf(mnA,__shfl_xor(mnA,16)); mnA=fminf(mnA,__shfl_xor(mnA,32));
        mxB=fmaxf(mxB,__shfl_xor(mxB,16)); mxB=fmaxf(mxB,__shfl_xor(mxB,32));
        mnB=fminf(mnB,__shfl_xor(mnB,16)); mnB=fminf(mnB,__shfl_xor(mnB,32));
        if (quad == 0) {
          int qid = q0 + (rt >> 1);
          Mmax[(size_t)qid*128 + colA] = mxA;  Mmin[(size_t)qid*128 + colA] = mnA;
          Mmax[(size_t)qid*128 + colB] = mxB;  Mmin[(size_t)qid*128 + colB] = mnB;
        }
      }
    }
    __syncthreads();
  }
  sA += __shfl_xor(sA,16); sA += __shfl_xor(sA,32);
  ssA += __shfl_xor(ssA,16); ssA += __shfl_xor(ssA,32);
  sB += __shfl_xor(sB,16); sB += __shfl_xor(sB,32);
  ssB += __shfl_xor(ssB,16); ssB += __shfl_xor(ssB,32);
  if (quad == 0) {
    p2[blockIdx.x*256 + colA]        = sA;
    p2[blockIdx.x*256 + 128 + colA]  = ssA;
    p2[blockIdx.x*256 + colB]        = sB;
    p2[blockIdx.x*256 + 128 + colB]  = ssB;
  }
}

// ---------------------------------------------------------------------------
// K7: out = relu(affine2(max-or-min)).
// ---------------------------------------------------------------------------
__global__ __launch_bounds__(256) void k_out(
    const float* __restrict__ Mmax, const float* __restrict__ Mmin,
    const float* __restrict__ par, float* __restrict__ out) {
  size_t e = (size_t)blockIdx.x*256 + threadIdx.x;
  int col = (int)(e & 127);
  float sc = par[256 + col], sh = par[384 + col];
  float m = (sc >= 0.f) ? Mmax[e] : Mmin[e];
  out[e] = fmaxf(fmaf(m, sc, sh), 0.f);
}

// ---------------------------------------------------------------------------
extern "C" void kernel_launch(void* const* d_in, const int* in_sizes, int n_in,
                              void* d_out, int out_size, void* d_ws, size_t ws_size,
                              hipStream_t stream) {
  const float* xyz    = (const float*)d_in[0];
  const float* points = (const float*)d_in[1];
  const float* W0     = (const float*)d_in[2];
  const float* b0     = (const float*)d_in[3];
  const float* g0     = (const float*)d_in[4];
  const float* beta0  = (const float*)d_in[5];
  const float* W1     = (const float*)d_in[6];
  const float* b1     = (const float*)d_in[7];
  const float* g1     = (const float*)d_in[8];
  const float* beta1  = (const float*)d_in[9];
  const float* W2     = (const float*)d_in[10];
  const float* b2     = (const float*)d_in[11];
  const float* g2     = (const float*)d_in[12];
  const float* beta2  = (const float*)d_in[13];

  char* ws = (char*)d_ws;
  float*     xyz4 = (float*)(ws + OFF_XYZ4);
  float*     Qb   = (float*)(ws + OFF_Q);
  float*     Rb   = (float*)(ws + OFF_R);
  int*       idxb = (int*)  (ws + OFF_IDX);
  _Float16*  W1h  = (_Float16*)(ws + OFF_W1H);
  _Float16*  W2h  = (_Float16*)(ws + OFF_W2H);
  float*     p0   = (float*)(ws + OFF_P0);
  float*     p1   = (float*)(ws + OFF_P1);
  float*     p2   = (float*)(ws + OFF_P2);
  float*     par  = (float*)(ws + OFF_PAR);
  float*     Mmax = (float*)(ws + OFF_MMAX);
  float*     Mmin = (float*)(ws + OFF_MMIN);
  float*     out  = (float*)d_out;

  hipLaunchKernelGGL(k_prep,  dim3(NQ/4), dim3(256), 0, stream, xyz, points, W0, b0, xyz4, Qb, Rb);
  hipLaunchKernelGGL(k_cast,  dim3(32),   dim3(256), 0, stream, W1, W2, W1h, W2h);
  hipLaunchKernelGGL(k_knn,   dim3(NQ/64), dim3(256), 0, stream, xyz4, idxb);
  hipLaunchKernelGGL(k_stats0,dim3(1024), dim3(256), 0, stream, Rb, Qb, idxb, p0);
  hipLaunchKernelGGL(k_fin,   dim3(1),    dim3(64),  0, stream, p0, 64, g0, beta0, par, 0);
  hipLaunchKernelGGL(k_l1,    dim3(1024), dim3(256), 0, stream, Rb, Qb, idxb, W1h, b1, par, p1);
  hipLaunchKernelGGL(k_fin,   dim3(1),    dim3(64),  0, stream, p1, 64, g1, beta1, par, 128);
  hipLaunchKernelGGL(k_l2,    dim3(1024), dim3(256), 0, stream, Rb, Qb, idxb, W1h, W2h, b1, b2, par, p2, Mmax, Mmin);
  hipLaunchKernelGGL(k_fin,   dim3(1),    dim3(128), 0, stream, p2, 128, g2, beta2, par, 256);
  hipLaunchKernelGGL(k_out,   dim3(out_size/256), dim3(256), 0, stream, Mmax, Mmin, par, out);
}

// Round 6
// 741.031 us; speedup vs baseline: 1.4034x; 1.4034x over previous
//
#include <hip/hip_runtime.h>

// ---------------------------------------------------------------------------
// PointNet++ set-abstraction block on MI355X.
// B=8, N=4096, K=32, D=64; out [B,N,128] fp32.
//  - layer0 linear decomposition: h0_pre = R[j] - Q[n]
//  - BN training-mode stats via per-block partials + finalize kernels
//  - layers 1/2 as fp16 MFMA (16x16x32) with fp32 accum
//  - max over K commutes with monotone BN affine: store max&min of h2 only
//  - kNN (R6): ONLY proven components. Pair-carrying wave insertion sort
//    (passed R1+R4) + tau prefilter (passed R4). Occupancy fix vs R4: no LDS
//    tile (global reads, L2-resident), 1 query/wave, dv[64] register cache,
//    launch_bounds(256,4). NO collection pass (failed identically R2/R3/R5).
// ---------------------------------------------------------------------------

using half8  = __attribute__((ext_vector_type(8))) _Float16;
using floatx4 = __attribute__((ext_vector_type(4))) float;

#define NB 8
#define NP 4096
#define NQ (NB*NP)          // 32768 points / queries
#define CNT_INV (1.0f/1048576.0f)   // 1/(B*N*K), exact power of two

// ---- workspace layout (bytes) ----
#define OFF_XYZ4  0ull
#define OFF_Q     (OFF_XYZ4 + (size_t)NQ*4*4)       // xyz4: x,y,z,|x|^2
#define OFF_R     (OFF_Q    + (size_t)NQ*64*4)
#define OFF_IDX   (OFF_R    + (size_t)NQ*64*4)
#define OFF_W1H   (OFF_IDX  + (size_t)NQ*32*4)
#define OFF_W2H   (OFF_W1H  + 4096*2)
#define OFF_P0    (OFF_W2H  + 8192*2)
#define OFF_P1    (OFF_P0   + (size_t)1024*128*4)
#define OFF_P2    (OFF_P1   + (size_t)1024*128*4)
#define OFF_PAR   (OFF_P2   + (size_t)1024*256*4)
#define OFF_MMAX  (OFF_PAR  + 512*4)
#define OFF_MMIN  (OFF_MMAX + (size_t)NQ*128*4)

// ---------------------------------------------------------------------------
// K0: per-point prep: xyz4=(x,y,z,sq), Q = W0_xyz@xyz, R = Q + W0_pts@pts + b0
// ---------------------------------------------------------------------------
__global__ __launch_bounds__(256) void k_prep(
    const float* __restrict__ xyz, const float* __restrict__ points,
    const float* __restrict__ W0, const float* __restrict__ b0,
    float* __restrict__ xyz4, float* __restrict__ Q, float* __restrict__ R) {
  __shared__ float w0s[64*67];
  for (int i = threadIdx.x; i < 64*67; i += 256) w0s[i] = W0[i];
  __syncthreads();
  int p = blockIdx.x*4 + (threadIdx.x >> 6);
  int o = threadIdx.x & 63;
  float x = xyz[p*3+0], y = xyz[p*3+1], z = xyz[p*3+2];
  const float* wr = w0s + o*67;
  float q = wr[0]*x + wr[1]*y + wr[2]*z;
  float r = b0[o] + q;
  const float* pp = points + (size_t)p*64;
  #pragma unroll 16
  for (int c = 0; c < 64; ++c) r = fmaf(wr[3+c], pp[c], r);
  Q[(size_t)p*64 + o] = q;
  R[(size_t)p*64 + o] = r;
  if (o == 0) {
    float sq = fmaf(x,x, fmaf(y,y, z*z));
    xyz4[p*4+0]=x; xyz4[p*4+1]=y; xyz4[p*4+2]=z; xyz4[p*4+3]=sq;
  }
}

// ---------------------------------------------------------------------------
// K0b: cast W1 (64x64), W2 (128x64) to fp16 row-major [o][c]
// ---------------------------------------------------------------------------
__global__ __launch_bounds__(256) void k_cast(
    const float* __restrict__ W1, const float* __restrict__ W2,
    _Float16* __restrict__ W1h, _Float16* __restrict__ W2h) {
  int t = blockIdx.x*256 + threadIdx.x;
  if (t < 4096) W1h[t] = (_Float16)W1[t];
  if (t < 8192) W2h[t] = (_Float16)W2[t];
}

// ---------------------------------------------------------------------------
// K1: exact kNN — proven pair insertion core (R1/R4) + proven tau filter (R4).
// One query per wave; candidates read from global (batch is 64 KB,
// L2-resident); distances cached in dv[64] registers.
// ---------------------------------------------------------------------------
__device__ __forceinline__ unsigned fmap(float f) {
  unsigned u = __float_as_uint(f);
  return u ^ ((unsigned)((int)u >> 31) | 0x80000000u);
}

__global__ __launch_bounds__(256, 4) void k_knn(
    const float* __restrict__ xyz4, int* __restrict__ idxb) {
  const int lane = threadIdx.x & 63;
  const int w = threadIdx.x >> 6;
  const int qid = blockIdx.x * 4 + w;     // 1024 blocks per batch: no straddle
  const int b = qid >> 12;
  const float4* xb = (const float4*)xyz4 + (size_t)b * NP;
  const float4 qv = xb[qid & (NP-1)];
  int* op = idxb + (size_t)qid * 32;

  // ---- pass 1: distances into registers + per-lane min (VMEM pipe) ----
  float dv[64];
  float mn = __uint_as_float(0x7F800000u);
  #pragma unroll
  for (int c = 0; c < 64; ++c) {
    float4 cd = xb[c*64 + lane];
    float dot = fmaf(qv.x, cd.x, fmaf(qv.y, cd.y, qv.z*cd.z));
    float d   = fmaf(-2.0f, dot, qv.w + cd.w);
    dv[c] = d;
    mn = fminf(mn, d);
  }
  // safe threshold: tau = max over lanes of per-lane min
  // (every lane's min <= tau => >=64 cands <= tau => top-32 subset of filter)
  float tau = mn;
  tau = fmaxf(tau, __shfl_xor(tau, 1));
  tau = fmaxf(tau, __shfl_xor(tau, 2));
  tau = fmaxf(tau, __shfl_xor(tau, 4));
  tau = fmaxf(tau, __shfl_xor(tau, 8));
  tau = fmaxf(tau, __shfl_xor(tau, 16));
  tau = fmaxf(tau, __shfl_xor(tau, 32));

  // ---- pass 2: R1/R4-proven pair insertion sort over {d <= tau} ----
  unsigned ku = 0xFFFFFFFFu;   // sorted dist keys, lanes 0..31 ascending
  int jv = 0;
  unsigned thr = 0xFFFFFFFFu;  // current 32nd-smallest key (wave uniform)
  #pragma unroll
  for (int c = 0; c < 64; ++c) {
    unsigned u = fmap(dv[c]);
    int j = c*64 + lane;
    unsigned long long ball = __ballot(dv[c] <= tau && u < thr);
    while (ball) {
      int src = __ffsll(ball) - 1;
      ball &= ball - 1;
      unsigned cu = __shfl(u, src);
      int cj = __shfl(j, src);
      if (cu < thr) {   // recheck: thr may have tightened
        unsigned long long m = __ballot(lane < 32 && ku < cu);
        int pos = __popcll(m);
        unsigned ku_up = __shfl_up(ku, 1);
        int jv_up = __shfl_up(jv, 1);
        if (lane < 32) {
          if (lane > pos)      { ku = ku_up; jv = jv_up; }
          else if (lane == pos){ ku = cu;    jv = cj;    }
        }
        thr = __shfl(ku, 31);
      }
    }
  }
  if (lane < 32) op[lane] = jv;
}

// ---------------------------------------------------------------------------
// K2: stats of h0_pre = R[j] - Q[n].  1024 blocks x 32 queries.
// ---------------------------------------------------------------------------
__global__ __launch_bounds__(256) void k_stats0(
    const float* __restrict__ R, const float* __restrict__ Q,
    const int* __restrict__ idxb, float* __restrict__ p0) {
  int o = threadIdx.x & 63, wg = threadIdx.x >> 6;
  float s = 0.f, ss = 0.f;
  for (int qi = 0; qi < 8; ++qi) {
    int qid = blockIdx.x*32 + wg*8 + qi;
    const float* Rb = R + (size_t)(qid & ~4095)*64;
    float qv = Q[(size_t)qid*64 + o];
    const int* ix = idxb + (size_t)qid*32;
    #pragma unroll 8
    for (int k = 0; k < 32; ++k) {
      float v = Rb[(size_t)ix[k]*64 + o] - qv;
      s += v; ss = fmaf(v, v, ss);
    }
  }
  __shared__ float red[512];
  red[threadIdx.x] = s; red[256 + threadIdx.x] = ss;
  __syncthreads();
  if (threadIdx.x < 64) {
    float S  = red[o] + red[64+o] + red[128+o] + red[192+o];
    float SS = red[256+o] + red[320+o] + red[384+o] + red[448+o];
    p0[blockIdx.x*128 + o]      = S;
    p0[blockIdx.x*128 + 64 + o] = SS;
  }
}

// ---------------------------------------------------------------------------
// K3: finalize BN stats -> affine params (scale, shift) at par[poff..]
// ---------------------------------------------------------------------------
__global__ void k_fin(const float* __restrict__ part, int C,
                      const float* __restrict__ g, const float* __restrict__ beta,
                      float* __restrict__ par, int poff) {
  int o = threadIdx.x;
  float S = 0.f, SS = 0.f;
  for (int s = 0; s < 1024; ++s) {
    S  += part[s*2*C + o];
    SS += part[s*2*C + C + o];
  }
  float mu  = S * CNT_INV;
  float var = SS * CNT_INV - mu*mu;
  float sc  = g[o] * rsqrtf(var + 1e-5f);
  par[poff + o]     = sc;
  par[poff + C + o] = beta[o] - mu*sc;
}

// ---------------------------------------------------------------------------
// K4: layer1 via fp16 MFMA; emit stats1 partials.
// ---------------------------------------------------------------------------
__global__ __launch_bounds__(256) void k_l1(
    const float* __restrict__ R, const float* __restrict__ Q,
    const int* __restrict__ idxb, const _Float16* __restrict__ W1h,
    const float* __restrict__ b1, const float* __restrict__ par,
    float* __restrict__ p1) {
  __shared__ __align__(16) _Float16 x1[128*72];
  int o = threadIdx.x & 63, wg = threadIdx.x >> 6;
  int m16 = o & 15, quad = o >> 4;
  float sc0 = par[o], sh0 = par[64 + o];
  int col = wg*16 + m16;
  half8 bf0 = *(const half8*)(W1h + col*64 + quad*8);
  half8 bf1 = *(const half8*)(W1h + col*64 + 32 + quad*8);
  float b1c = b1[col];
  float s = 0.f, ss = 0.f;

  for (int gi = 0; gi < 8; ++gi) {
    int q0 = (blockIdx.x*8 + gi) * 4;
    {
      int qid = q0 + wg;
      const float* Rb = R + (size_t)(qid & ~4095)*64;
      float qv = Q[(size_t)qid*64 + o];
      const int* ix = idxb + (size_t)qid*32;
      #pragma unroll 4
      for (int r = 0; r < 32; ++r) {
        float v = fmaf(Rb[(size_t)ix[r]*64 + o] - qv, sc0, sh0);
        x1[(wg*32 + r)*72 + o] = (_Float16)fmaxf(v, 0.f);
      }
    }
    __syncthreads();
    #pragma unroll
    for (int rt = 0; rt < 8; ++rt) {
      const _Float16* ap = x1 + (rt*16 + m16)*72 + quad*8;
      half8 a0 = *(const half8*)(ap);
      half8 a1 = *(const half8*)(ap + 32);
      floatx4 acc = {0.f,0.f,0.f,0.f};
      acc = __builtin_amdgcn_mfma_f32_16x16x32_f16(a0, bf0, acc, 0,0,0);
      acc = __builtin_amdgcn_mfma_f32_16x16x32_f16(a1, bf1, acc, 0,0,0);
      #pragma unroll
      for (int rg = 0; rg < 4; ++rg) {
        float h = acc[rg] + b1c;
        s += h; ss = fmaf(h, h, ss);
      }
    }
    __syncthreads();
  }
  s  += __shfl_xor(s, 16);  s  += __shfl_xor(s, 32);
  ss += __shfl_xor(ss, 16); ss += __shfl_xor(ss, 32);
  if (quad == 0) {
    p1[blockIdx.x*128 + col]      = s;
    p1[blockIdx.x*128 + 64 + col] = ss;
  }
}

// ---------------------------------------------------------------------------
// K6: layer1 (recompute) -> bn1+relu -> layer2 MFMA -> stats2 + max/min
// ---------------------------------------------------------------------------
__global__ __launch_bounds__(256) void k_l2(
    const float* __restrict__ R, const float* __restrict__ Q,
    const int* __restrict__ idxb, const _Float16* __restrict__ W1h,
    const _Float16* __restrict__ W2h, const float* __restrict__ b1,
    const float* __restrict__ b2, const float* __restrict__ par,
    float* __restrict__ p2, float* __restrict__ Mmax, float* __restrict__ Mmin) {
  __shared__ __align__(16) _Float16 x1[128*72];
  __shared__ __align__(16) _Float16 x2[128*72];
  int o = threadIdx.x & 63, wg = threadIdx.x >> 6;
  int m16 = o & 15, quad = o >> 4;
  float sc0 = par[o], sh0 = par[64 + o];
  int col1 = wg*16 + m16;
  float sc1 = par[128 + col1], sh1 = par[192 + col1];
  half8 b1f0 = *(const half8*)(W1h + col1*64 + quad*8);
  half8 b1f1 = *(const half8*)(W1h + col1*64 + 32 + quad*8);
  float b1c = b1[col1];
  int colA = wg*16 + m16, colB = 64 + wg*16 + m16;
  half8 b2A0 = *(const half8*)(W2h + colA*64 + quad*8);
  half8 b2A1 = *(const half8*)(W2h + colA*64 + 32 + quad*8);
  half8 b2B0 = *(const half8*)(W2h + colB*64 + quad*8);
  half8 b2B1 = *(const half8*)(W2h + colB*64 + 32 + quad*8);
  float b2a = b2[colA], b2b = b2[colB];
  float sA=0.f, ssA=0.f, sB=0.f, ssB=0.f;

  for (int gi = 0; gi < 8; ++gi) {
    int q0 = (blockIdx.x*8 + gi) * 4;
    {
      int qid = q0 + wg;
      const float* Rb = R + (size_t)(qid & ~4095)*64;
      float qv = Q[(size_t)qid*64 + o];
      const int* ix = idxb + (size_t)qid*32;
      #pragma unroll 4
      for (int r = 0; r < 32; ++r) {
        float v = fmaf(Rb[(size_t)ix[r]*64 + o] - qv, sc0, sh0);
        x1[(wg*32 + r)*72 + o] = (_Float16)fmaxf(v, 0.f);
      }
    }
    __syncthreads();
    #pragma unroll
    for (int rt = 0; rt < 8; ++rt) {
      const _Float16* ap = x1 + (rt*16 + m16)*72 + quad*8;
      half8 a0 = *(const half8*)(ap);
      half8 a1 = *(const half8*)(ap + 32);
      floatx4 acc = {0.f,0.f,0.f,0.f};
      acc = __builtin_amdgcn_mfma_f32_16x16x32_f16(a0, b1f0, acc, 0,0,0);
      acc = __builtin_amdgcn_mfma_f32_16x16x32_f16(a1, b1f1, acc, 0,0,0);
      #pragma unroll
      for (int rg = 0; rg < 4; ++rg) {
        float h = acc[rg] + b1c;
        float v = fmaxf(fmaf(h, sc1, sh1), 0.f);
        x2[(rt*16 + quad*4 + rg)*72 + col1] = (_Float16)v;
      }
    }
    __syncthreads();
    float mxA=0.f, mnA=0.f, mxB=0.f, mnB=0.f;
    #pragma unroll
    for (int rt = 0; rt < 8; ++rt) {
      const _Float16* ap = x2 + (rt*16 + m16)*72 + quad*8;
      half8 a0 = *(const half8*)(ap);
      half8 a1 = *(const half8*)(ap + 32);
      floatx4 accA = {0.f,0.f,0.f,0.f}, accB = {0.f,0.f,0.f,0.f};
      accA = __builtin_amdgcn_mfma_f32_16x16x32_f16(a0, b2A0, accA, 0,0,0);
      accA = __builtin_amdgcn_mfma_f32_16x16x32_f16(a1, b2A1, accA, 0,0,0);
      accB = __builtin_amdgcn_mfma_f32_16x16x32_f16(a0, b2B0, accB, 0,0,0);
      accB = __builtin_amdgcn_mfma_f32_16x16x32_f16(a1, b2B1, accB, 0,0,0);
      float hA0 = accA[0]+b2a, hA1 = accA[1]+b2a, hA2 = accA[2]+b2a, hA3 = accA[3]+b2a;
      float hB0 = accB[0]+b2b, hB1 = accB[1]+b2b, hB2 = accB[2]+b2b, hB3 = accB[3]+b2b;
      sA += hA0+hA1+hA2+hA3;
      ssA = fmaf(hA0,hA0, fmaf(hA1,hA1, fmaf(hA2,hA2, fmaf(hA3,hA3, ssA))));
      sB += hB0+hB1+hB2+hB3;
      ssB = fmaf(hB0,hB0, fmaf(hB1,hB1, fmaf(hB2,hB2, fmaf(hB3,hB3, ssB))));
      float m4A = fmaxf(fmaxf(hA0,hA1), fmaxf(hA2,hA3));
      float n4A = fminf(fminf(hA0,hA1), fminf(hA2,hA3));
      float m4B = fmaxf(fmaxf(hB0,hB1), fmaxf(hB2,hB3));
      float n4B = fminf(fminf(hB0,hB1), fminf(hB2,hB3));
      if ((rt & 1) == 0) { mxA=m4A; mnA=n4A; mxB=m4B; mnB=n4B; }
      else {
        mxA=fmaxf(mxA,m4A); mnA=fminf(mnA,n4A);
        mxB=fmaxf(mxB,m4B); mnB=fminf(mnB,n4B);
        mxA=fmaxf(mxA,__shfl_xor(mxA,16)); mxA=fmaxf(mxA,__shfl_xor(mxA,32));
        mnA=fminf(mnA,__shfl_xor(mnA,16)); mnA=fminf(mnA,__shfl_xor(mnA,32));
        mxB=fmaxf(mxB,__shfl_xor(mxB,16)); mxB=fmaxf(mxB,__shfl_xor(mxB,32));
        mnB=fminf(mnB,__shfl_xor(mnB,16)); mnB=fminf(mnB,__shfl_xor(mnB,32));
        if (quad == 0) {
          int qid = q0 + (rt >> 1);
          Mmax[(size_t)qid*128 + colA] = mxA;  Mmin[(size_t)qid*128 + colA] = mnA;
          Mmax[(size_t)qid*128 + colB] = mxB;  Mmin[(size_t)qid*128 + colB] = mnB;
        }
      }
    }
    __syncthreads();
  }
  sA += __shfl_xor(sA,16); sA += __shfl_xor(sA,32);
  ssA += __shfl_xor(ssA,16); ssA += __shfl_xor(ssA,32);
  sB += __shfl_xor(sB,16); sB += __shfl_xor(sB,32);
  ssB += __shfl_xor(ssB,16); ssB += __shfl_xor(ssB,32);
  if (quad == 0) {
    p2[blockIdx.x*256 + colA]        = sA;
    p2[blockIdx.x*256 + 128 + colA]  = ssA;
    p2[blockIdx.x*256 + colB]        = sB;
    p2[blockIdx.x*256 + 128 + colB]  = ssB;
  }
}

// ---------------------------------------------------------------------------
// K7: out = relu(affine2(max-or-min)).
// ---------------------------------------------------------------------------
__global__ __launch_bounds__(256) void k_out(
    const float* __restrict__ Mmax, const float* __restrict__ Mmin,
    const float* __restrict__ par, float* __restrict__ out) {
  size_t e = (size_t)blockIdx.x*256 + threadIdx.x;
  int col = (int)(e & 127);
  float sc = par[256 + col], sh = par[384 + col];
  float m = (sc >= 0.f) ? Mmax[e] : Mmin[e];
  out[e] = fmaxf(fmaf(m, sc, sh), 0.f);
}

// ---------------------------------------------------------------------------
extern "C" void kernel_launch(void* const* d_in, const int* in_sizes, int n_in,
                              void* d_out, int out_size, void* d_ws, size_t ws_size,
                              hipStream_t stream) {
  const float* xyz    = (const float*)d_in[0];
  const float* points = (const float*)d_in[1];
  const float* W0     = (const float*)d_in[2];
  const float* b0     = (const float*)d_in[3];
  const float* g0     = (const float*)d_in[4];
  const float* beta0  = (const float*)d_in[5];
  const float* W1     = (const float*)d_in[6];
  const float* b1     = (const float*)d_in[7];
  const float* g1     = (const float*)d_in[8];
  const float* beta1  = (const float*)d_in[9];
  const float* W2     = (const float*)d_in[10];
  const float* b2     = (const float*)d_in[11];
  const float* g2     = (const float*)d_in[12];
  const float* beta2  = (const float*)d_in[13];

  char* ws = (char*)d_ws;
  float*     xyz4 = (float*)(ws + OFF_XYZ4);
  float*     Qb   = (float*)(ws + OFF_Q);
  float*     Rb   = (float*)(ws + OFF_R);
  int*       idxb = (int*)  (ws + OFF_IDX);
  _Float16*  W1h  = (_Float16*)(ws + OFF_W1H);
  _Float16*  W2h  = (_Float16*)(ws + OFF_W2H);
  float*     p0   = (float*)(ws + OFF_P0);
  float*     p1   = (float*)(ws + OFF_P1);
  float*     p2   = (float*)(ws + OFF_P2);
  float*     par  = (float*)(ws + OFF_PAR);
  float*     Mmax = (float*)(ws + OFF_MMAX);
  float*     Mmin = (float*)(ws + OFF_MMIN);
  float*     out  = (float*)d_out;

  hipLaunchKernelGGL(k_prep,  dim3(NQ/4), dim3(256), 0, stream, xyz, points, W0, b0, xyz4, Qb, Rb);
  hipLaunchKernelGGL(k_cast,  dim3(32),   dim3(256), 0, stream, W1, W2, W1h, W2h);
  hipLaunchKernelGGL(k_knn,   dim3(NQ/4), dim3(256), 0, stream, xyz4, idxb);
  hipLaunchKernelGGL(k_stats0,dim3(1024), dim3(256), 0, stream, Rb, Qb, idxb, p0);
  hipLaunchKernelGGL(k_fin,   dim3(1),    dim3(64),  0, stream, p0, 64, g0, beta0, par, 0);
  hipLaunchKernelGGL(k_l1,    dim3(1024), dim3(256), 0, stream, Rb, Qb, idxb, W1h, b1, par, p1);
  hipLaunchKernelGGL(k_fin,   dim3(1),    dim3(64),  0, stream, p1, 64, g1, beta1, par, 128);
  hipLaunchKernelGGL(k_l2,    dim3(1024), dim3(256), 0, stream, Rb, Qb, idxb, W1h, W2h, b1, b2, par, p2, Mmax, Mmin);
  hipLaunchKernelGGL(k_fin,   dim3(1),    dim3(128), 0, stream, p2, 128, g2, beta2, par, 256);
  hipLaunchKernelGGL(k_out,   dim3(out_size/256), dim3(256), 0, stream, Mmax, Mmin, par, out);
}

// Round 7
// 587.663 us; speedup vs baseline: 1.7696x; 1.2610x over previous
//
#include <hip/hip_runtime.h>

// ---------------------------------------------------------------------------
// PointNet++ set-abstraction block on MI355X.
// B=8, N=4096, K=32, D=64; out [B,N,128] fp32.
//  - layer0 linear decomposition: h0_pre = R[j] - Q[n]
//  - BN training-mode stats via per-block partials + finalize kernels
//  - layers 1/2 as fp16 MFMA (16x16x32) with fp32 accum
//  - max over K commutes with monotone BN affine: store max&min of h2 only
//  - kNN (R7): proven pair-insertion core (R1/R4/R6). Spill fix: chunk A
//    (32 cands/lane) register-cached, chunk B streamed (never stored).
//    Tight safe tau: 32nd-smallest of chunk-A lane-mins via integer ballot
//    bisection (>=32 real distances <= tau => top-32 within filter).
//    readlane replaces broadcast shfls (2 DS ops/insert instead of 5).
// ---------------------------------------------------------------------------

using half8  = __attribute__((ext_vector_type(8))) _Float16;
using floatx4 = __attribute__((ext_vector_type(4))) float;

#define NB 8
#define NP 4096
#define NQ (NB*NP)          // 32768 points / queries
#define CNT_INV (1.0f/1048576.0f)   // 1/(B*N*K), exact power of two

// ---- workspace layout (bytes) ----
#define OFF_XYZ4  0ull
#define OFF_Q     (OFF_XYZ4 + (size_t)NQ*4*4)       // xyz4: x,y,z,|x|^2
#define OFF_R     (OFF_Q    + (size_t)NQ*64*4)
#define OFF_IDX   (OFF_R    + (size_t)NQ*64*4)
#define OFF_W1H   (OFF_IDX  + (size_t)NQ*32*4)
#define OFF_W2H   (OFF_W1H  + 4096*2)
#define OFF_P0    (OFF_W2H  + 8192*2)
#define OFF_P1    (OFF_P0   + (size_t)1024*128*4)
#define OFF_P2    (OFF_P1   + (size_t)1024*128*4)
#define OFF_PAR   (OFF_P2   + (size_t)1024*256*4)
#define OFF_MMAX  (OFF_PAR  + 512*4)
#define OFF_MMIN  (OFF_MMAX + (size_t)NQ*128*4)

// ---------------------------------------------------------------------------
// K0: per-point prep: xyz4=(x,y,z,sq), Q = W0_xyz@xyz, R = Q + W0_pts@pts + b0
// ---------------------------------------------------------------------------
__global__ __launch_bounds__(256) void k_prep(
    const float* __restrict__ xyz, const float* __restrict__ points,
    const float* __restrict__ W0, const float* __restrict__ b0,
    float* __restrict__ xyz4, float* __restrict__ Q, float* __restrict__ R) {
  __shared__ float w0s[64*67];
  for (int i = threadIdx.x; i < 64*67; i += 256) w0s[i] = W0[i];
  __syncthreads();
  int p = blockIdx.x*4 + (threadIdx.x >> 6);
  int o = threadIdx.x & 63;
  float x = xyz[p*3+0], y = xyz[p*3+1], z = xyz[p*3+2];
  const float* wr = w0s + o*67;
  float q = wr[0]*x + wr[1]*y + wr[2]*z;
  float r = b0[o] + q;
  const float* pp = points + (size_t)p*64;
  #pragma unroll 16
  for (int c = 0; c < 64; ++c) r = fmaf(wr[3+c], pp[c], r);
  Q[(size_t)p*64 + o] = q;
  R[(size_t)p*64 + o] = r;
  if (o == 0) {
    float sq = fmaf(x,x, fmaf(y,y, z*z));
    xyz4[p*4+0]=x; xyz4[p*4+1]=y; xyz4[p*4+2]=z; xyz4[p*4+3]=sq;
  }
}

// ---------------------------------------------------------------------------
// K0b: cast W1 (64x64), W2 (128x64) to fp16 row-major [o][c]
// ---------------------------------------------------------------------------
__global__ __launch_bounds__(256) void k_cast(
    const float* __restrict__ W1, const float* __restrict__ W2,
    _Float16* __restrict__ W1h, _Float16* __restrict__ W2h) {
  int t = blockIdx.x*256 + threadIdx.x;
  if (t < 4096) W1h[t] = (_Float16)W1[t];
  if (t < 8192) W2h[t] = (_Float16)W2[t];
}

// ---------------------------------------------------------------------------
// K1: exact kNN.
// ---------------------------------------------------------------------------
__device__ __forceinline__ unsigned fmap(float f) {
  unsigned u = __float_as_uint(f);
  return u ^ ((unsigned)((int)u >> 31) | 0x80000000u);
}

// one insertion round of the R1/R6-proven core (2 DS ops per insert)
#define INSERT_ROUND(uu, jj)                                                  \
  {                                                                           \
    unsigned long long ball = __ballot((uu) <= utau && (uu) < thr);           \
    while (ball) {                                                            \
      int src = __ffsll(ball) - 1;                                            \
      ball &= ball - 1;                                                       \
      unsigned cu = (unsigned)__builtin_amdgcn_readlane((int)(uu), src);      \
      int cj = __builtin_amdgcn_readlane((jj), src);                          \
      if (cu < thr) {                                                         \
        unsigned long long m = __ballot(lane < 32 && ku < cu);                \
        int pos = __popcll(m);                                                \
        unsigned ku_up = __shfl_up(ku, 1);                                    \
        int jv_up = __shfl_up(jv, 1);                                         \
        if (lane < 32) {                                                      \
          if (lane > pos)      { ku = ku_up; jv = jv_up; }                    \
          else if (lane == pos){ ku = cu;    jv = cj;    }                    \
        }                                                                     \
        thr = (unsigned)__builtin_amdgcn_readlane((int)ku, 31);               \
      }                                                                       \
    }                                                                         \
  }

__global__ __launch_bounds__(256, 6) void k_knn(
    const float* __restrict__ xyz4, int* __restrict__ idxb) {
  const int lane = threadIdx.x & 63;
  const int w = threadIdx.x >> 6;
  const int qid = blockIdx.x * 4 + w;     // 1024 blocks per batch: no straddle
  const int b = qid >> 12;
  const float4* xb = (const float4*)xyz4 + (size_t)b * NP;
  const float4 qv = xb[qid & (NP-1)];
  int* op = idxb + (size_t)qid * 32;

  // ---- chunk A (c=0..31): distances into 32 regs + per-lane min ----
  float dvA[32];
  float mn = __uint_as_float(0x7F800000u);
  #pragma unroll
  for (int c = 0; c < 32; ++c) {
    float4 cd = xb[c*64 + lane];
    float dot = fmaf(qv.x, cd.x, fmaf(qv.y, cd.y, qv.z*cd.z));
    float d   = fmaf(-2.0f, dot, qv.w + cd.w);
    dvA[c] = d;
    mn = fminf(mn, d);
  }

  // ---- safe tau: 32nd-smallest of the 64 chunk-A lane-mins (int bisect).
  //      Invariant: count(lane-min keys <= hi) >= 32 (init: 64).  Those 32
  //      lane-mins are real distances => >=32 cands <= tau => top-32 subset.
  const unsigned mu = fmap(mn);
  unsigned lo = 0u, hi = 0xFFFFFFFFu;
  for (int it = 0; it < 32; ++it) {
    unsigned mid = lo + ((hi - lo) >> 1);
    int cnt = __popcll(__ballot(mu <= mid));
    if (cnt >= 32) hi = mid; else lo = mid + 1;
  }
  const unsigned utau = hi;

  // ---- insertion sort (proven core), chunk A from regs ----
  unsigned ku = 0xFFFFFFFFu;   // sorted dist keys, lanes 0..31 ascending
  int jv = 0;
  unsigned thr = 0xFFFFFFFFu;  // current 32nd-smallest key (wave uniform)
  #pragma unroll
  for (int c = 0; c < 32; ++c) {
    unsigned u = fmap(dvA[c]);
    int j = c*64 + lane;
    INSERT_ROUND(u, j)
  }
  // ---- chunk B (c=32..63): streamed, never stored ----
  #pragma unroll 8
  for (int c = 32; c < 64; ++c) {
    float4 cd = xb[c*64 + lane];
    float dot = fmaf(qv.x, cd.x, fmaf(qv.y, cd.y, qv.z*cd.z));
    float d   = fmaf(-2.0f, dot, qv.w + cd.w);
    unsigned u = fmap(d);
    int j = c*64 + lane;
    INSERT_ROUND(u, j)
  }
  if (lane < 32) op[lane] = jv;
}

// ---------------------------------------------------------------------------
// K2: stats of h0_pre = R[j] - Q[n].  1024 blocks x 32 queries.
// ---------------------------------------------------------------------------
__global__ __launch_bounds__(256) void k_stats0(
    const float* __restrict__ R, const float* __restrict__ Q,
    const int* __restrict__ idxb, float* __restrict__ p0) {
  int o = threadIdx.x & 63, wg = threadIdx.x >> 6;
  float s = 0.f, ss = 0.f;
  for (int qi = 0; qi < 8; ++qi) {
    int qid = blockIdx.x*32 + wg*8 + qi;
    const float* Rb = R + (size_t)(qid & ~4095)*64;
    float qv = Q[(size_t)qid*64 + o];
    const int* ix = idxb + (size_t)qid*32;
    #pragma unroll 8
    for (int k = 0; k < 32; ++k) {
      float v = Rb[(size_t)ix[k]*64 + o] - qv;
      s += v; ss = fmaf(v, v, ss);
    }
  }
  __shared__ float red[512];
  red[threadIdx.x] = s; red[256 + threadIdx.x] = ss;
  __syncthreads();
  if (threadIdx.x < 64) {
    float S  = red[o] + red[64+o] + red[128+o] + red[192+o];
    float SS = red[256+o] + red[320+o] + red[384+o] + red[448+o];
    p0[blockIdx.x*128 + o]      = S;
    p0[blockIdx.x*128 + 64 + o] = SS;
  }
}

// ---------------------------------------------------------------------------
// K3: finalize BN stats -> affine params (scale, shift) at par[poff..]
// ---------------------------------------------------------------------------
__global__ void k_fin(const float* __restrict__ part, int C,
                      const float* __restrict__ g, const float* __restrict__ beta,
                      float* __restrict__ par, int poff) {
  int o = threadIdx.x;
  float S = 0.f, SS = 0.f;
  for (int s = 0; s < 1024; ++s) {
    S  += part[s*2*C + o];
    SS += part[s*2*C + C + o];
  }
  float mu  = S * CNT_INV;
  float var = SS * CNT_INV - mu*mu;
  float sc  = g[o] * rsqrtf(var + 1e-5f);
  par[poff + o]     = sc;
  par[poff + C + o] = beta[o] - mu*sc;
}

// ---------------------------------------------------------------------------
// K4: layer1 via fp16 MFMA; emit stats1 partials.
// ---------------------------------------------------------------------------
__global__ __launch_bounds__(256) void k_l1(
    const float* __restrict__ R, const float* __restrict__ Q,
    const int* __restrict__ idxb, const _Float16* __restrict__ W1h,
    const float* __restrict__ b1, const float* __restrict__ par,
    float* __restrict__ p1) {
  __shared__ __align__(16) _Float16 x1[128*72];
  int o = threadIdx.x & 63, wg = threadIdx.x >> 6;
  int m16 = o & 15, quad = o >> 4;
  float sc0 = par[o], sh0 = par[64 + o];
  int col = wg*16 + m16;
  half8 bf0 = *(const half8*)(W1h + col*64 + quad*8);
  half8 bf1 = *(const half8*)(W1h + col*64 + 32 + quad*8);
  float b1c = b1[col];
  float s = 0.f, ss = 0.f;

  for (int gi = 0; gi < 8; ++gi) {
    int q0 = (blockIdx.x*8 + gi) * 4;
    {
      int qid = q0 + wg;
      const float* Rb = R + (size_t)(qid & ~4095)*64;
      float qv = Q[(size_t)qid*64 + o];
      const int* ix = idxb + (size_t)qid*32;
      #pragma unroll 4
      for (int r = 0; r < 32; ++r) {
        float v = fmaf(Rb[(size_t)ix[r]*64 + o] - qv, sc0, sh0);
        x1[(wg*32 + r)*72 + o] = (_Float16)fmaxf(v, 0.f);
      }
    }
    __syncthreads();
    #pragma unroll
    for (int rt = 0; rt < 8; ++rt) {
      const _Float16* ap = x1 + (rt*16 + m16)*72 + quad*8;
      half8 a0 = *(const half8*)(ap);
      half8 a1 = *(const half8*)(ap + 32);
      floatx4 acc = {0.f,0.f,0.f,0.f};
      acc = __builtin_amdgcn_mfma_f32_16x16x32_f16(a0, bf0, acc, 0,0,0);
      acc = __builtin_amdgcn_mfma_f32_16x16x32_f16(a1, bf1, acc, 0,0,0);
      #pragma unroll
      for (int rg = 0; rg < 4; ++rg) {
        float h = acc[rg] + b1c;
        s += h; ss = fmaf(h, h, ss);
      }
    }
    __syncthreads();
  }
  s  += __shfl_xor(s, 16);  s  += __shfl_xor(s, 32);
  ss += __shfl_xor(ss, 16); ss += __shfl_xor(ss, 32);
  if (quad == 0) {
    p1[blockIdx.x*128 + col]      = s;
    p1[blockIdx.x*128 + 64 + col] = ss;
  }
}

// ---------------------------------------------------------------------------
// K6: layer1 (recompute) -> bn1+relu -> layer2 MFMA -> stats2 + max/min
// ---------------------------------------------------------------------------
__global__ __launch_bounds__(256) void k_l2(
    const float* __restrict__ R, const float* __restrict__ Q,
    const int* __restrict__ idxb, const _Float16* __restrict__ W1h,
    const _Float16* __restrict__ W2h, const float* __restrict__ b1,
    const float* __restrict__ b2, const float* __restrict__ par,
    float* __restrict__ p2, float* __restrict__ Mmax, float* __restrict__ Mmin) {
  __shared__ __align__(16) _Float16 x1[128*72];
  __shared__ __align__(16) _Float16 x2[128*72];
  int o = threadIdx.x & 63, wg = threadIdx.x >> 6;
  int m16 = o & 15, quad = o >> 4;
  float sc0 = par[o], sh0 = par[64 + o];
  int col1 = wg*16 + m16;
  float sc1 = par[128 + col1], sh1 = par[192 + col1];
  half8 b1f0 = *(const half8*)(W1h + col1*64 + quad*8);
  half8 b1f1 = *(const half8*)(W1h + col1*64 + 32 + quad*8);
  float b1c = b1[col1];
  int colA = wg*16 + m16, colB = 64 + wg*16 + m16;
  half8 b2A0 = *(const half8*)(W2h + colA*64 + quad*8);
  half8 b2A1 = *(const half8*)(W2h + colA*64 + 32 + quad*8);
  half8 b2B0 = *(const half8*)(W2h + colB*64 + quad*8);
  half8 b2B1 = *(const half8*)(W2h + colB*64 + 32 + quad*8);
  float b2a = b2[colA], b2b = b2[colB];
  float sA=0.f, ssA=0.f, sB=0.f, ssB=0.f;

  for (int gi = 0; gi < 8; ++gi) {
    int q0 = (blockIdx.x*8 + gi) * 4;
    {
      int qid = q0 + wg;
      const float* Rb = R + (size_t)(qid & ~4095)*64;
      float qv = Q[(size_t)qid*64 + o];
      const int* ix = idxb + (size_t)qid*32;
      #pragma unroll 4
      for (int r = 0; r < 32; ++r) {
        float v = fmaf(Rb[(size_t)ix[r]*64 + o] - qv, sc0, sh0);
        x1[(wg*32 + r)*72 + o] = (_Float16)fmaxf(v, 0.f);
      }
    }
    __syncthreads();
    #pragma unroll
    for (int rt = 0; rt < 8; ++rt) {
      const _Float16* ap = x1 + (rt*16 + m16)*72 + quad*8;
      half8 a0 = *(const half8*)(ap);
      half8 a1 = *(const half8*)(ap + 32);
      floatx4 acc = {0.f,0.f,0.f,0.f};
      acc = __builtin_amdgcn_mfma_f32_16x16x32_f16(a0, b1f0, acc, 0,0,0);
      acc = __builtin_amdgcn_mfma_f32_16x16x32_f16(a1, b1f1, acc, 0,0,0);
      #pragma unroll
      for (int rg = 0; rg < 4; ++rg) {
        float h = acc[rg] + b1c;
        float v = fmaxf(fmaf(h, sc1, sh1), 0.f);
        x2[(rt*16 + quad*4 + rg)*72 + col1] = (_Float16)v;
      }
    }
    __syncthreads();
    float mxA=0.f, mnA=0.f, mxB=0.f, mnB=0.f;
    #pragma unroll
    for (int rt = 0; rt < 8; ++rt) {
      const _Float16* ap = x2 + (rt*16 + m16)*72 + quad*8;
      half8 a0 = *(const half8*)(ap);
      half8 a1 = *(const half8*)(ap + 32);
      floatx4 accA = {0.f,0.f,0.f,0.f}, accB = {0.f,0.f,0.f,0.f};
      accA = __builtin_amdgcn_mfma_f32_16x16x32_f16(a0, b2A0, accA, 0,0,0);
      accA = __builtin_amdgcn_mfma_f32_16x16x32_f16(a1, b2A1, accA, 0,0,0);
      accB = __builtin_amdgcn_mfma_f32_16x16x32_f16(a0, b2B0, accB, 0,0,0);
      accB = __builtin_amdgcn_mfma_f32_16x16x32_f16(a1, b2B1, accB, 0,0,0);
      float hA0 = accA[0]+b2a, hA1 = accA[1]+b2a, hA2 = accA[2]+b2a, hA3 = accA[3]+b2a;
      float hB0 = accB[0]+b2b, hB1 = accB[1]+b2b, hB2 = accB[2]+b2b, hB3 = accB[3]+b2b;
      sA += hA0+hA1+hA2+hA3;
      ssA = fmaf(hA0,hA0, fmaf(hA1,hA1, fmaf(hA2,hA2, fmaf(hA3,hA3, ssA))));
      sB += hB0+hB1+hB2+hB3;
      ssB = fmaf(hB0,hB0, fmaf(hB1,hB1, fmaf(hB2,hB2, fmaf(hB3,hB3, ssB))));
      float m4A = fmaxf(fmaxf(hA0,hA1), fmaxf(hA2,hA3));
      float n4A = fminf(fminf(hA0,hA1), fminf(hA2,hA3));
      float m4B = fmaxf(fmaxf(hB0,hB1), fmaxf(hB2,hB3));
      float n4B = fminf(fminf(hB0,hB1), fminf(hB2,hB3));
      if ((rt & 1) == 0) { mxA=m4A; mnA=n4A; mxB=m4B; mnB=n4B; }
      else {
        mxA=fmaxf(mxA,m4A); mnA=fminf(mnA,n4A);
        mxB=fmaxf(mxB,m4B); mnB=fminf(mnB,n4B);
        mxA=fmaxf(mxA,__shfl_xor(mxA,16)); mxA=fmaxf(mxA,__shfl_xor(mxA,32));
        mnA=fminf(mnA,__shfl_xor(mnA,16)); mnA=fminf(mnA,__shfl_xor(mnA,32));
        mxB=fmaxf(mxB,__shfl_xor(mxB,16)); mxB=fmaxf(mxB,__shfl_xor(mxB,32));
        mnB=fminf(mnB,__shfl_xor(mnB,16)); mnB=fminf(mnB,__shfl_xor(mnB,32));
        if (quad == 0) {
          int qid = q0 + (rt >> 1);
          Mmax[(size_t)qid*128 + colA] = mxA;  Mmin[(size_t)qid*128 + colA] = mnA;
          Mmax[(size_t)qid*128 + colB] = mxB;  Mmin[(size_t)qid*128 + colB] = mnB;
        }
      }
    }
    __syncthreads();
  }
  sA += __shfl_xor(sA,16); sA += __shfl_xor(sA,32);
  ssA += __shfl_xor(ssA,16); ssA += __shfl_xor(ssA,32);
  sB += __shfl_xor(sB,16); sB += __shfl_xor(sB,32);
  ssB += __shfl_xor(ssB,16); ssB += __shfl_xor(ssB,32);
  if (quad == 0) {
    p2[blockIdx.x*256 + colA]        = sA;
    p2[blockIdx.x*256 + 128 + colA]  = ssA;
    p2[blockIdx.x*256 + colB]        = sB;
    p2[blockIdx.x*256 + 128 + colB]  = ssB;
  }
}

// ---------------------------------------------------------------------------
// K7: out = relu(affine2(max-or-min)).
// ---------------------------------------------------------------------------
__global__ __launch_bounds__(256) void k_out(
    const float* __restrict__ Mmax, const float* __restrict__ Mmin,
    const float* __restrict__ par, float* __restrict__ out) {
  size_t e = (size_t)blockIdx.x*256 + threadIdx.x;
  int col = (int)(e & 127);
  float sc = par[256 + col], sh = par[384 + col];
  float m = (sc >= 0.f) ? Mmax[e] : Mmin[e];
  out[e] = fmaxf(fmaf(m, sc, sh), 0.f);
}

// ---------------------------------------------------------------------------
extern "C" void kernel_launch(void* const* d_in, const int* in_sizes, int n_in,
                              void* d_out, int out_size, void* d_ws, size_t ws_size,
                              hipStream_t stream) {
  const float* xyz    = (const float*)d_in[0];
  const float* points = (const float*)d_in[1];
  const float* W0     = (const float*)d_in[2];
  const float* b0     = (const float*)d_in[3];
  const float* g0     = (const float*)d_in[4];
  const float* beta0  = (const float*)d_in[5];
  const float* W1     = (const float*)d_in[6];
  const float* b1     = (const float*)d_in[7];
  const float* g1     = (const float*)d_in[8];
  const float* beta1  = (const float*)d_in[9];
  const float* W2     = (const float*)d_in[10];
  const float* b2     = (const float*)d_in[11];
  const float* g2     = (const float*)d_in[12];
  const float* beta2  = (const float*)d_in[13];

  char* ws = (char*)d_ws;
  float*     xyz4 = (float*)(ws + OFF_XYZ4);
  float*     Qb   = (float*)(ws + OFF_Q);
  float*     Rb   = (float*)(ws + OFF_R);
  int*       idxb = (int*)  (ws + OFF_IDX);
  _Float16*  W1h  = (_Float16*)(ws + OFF_W1H);
  _Float16*  W2h  = (_Float16*)(ws + OFF_W2H);
  float*     p0   = (float*)(ws + OFF_P0);
  float*     p1   = (float*)(ws + OFF_P1);
  float*     p2   = (float*)(ws + OFF_P2);
  float*     par  = (float*)(ws + OFF_PAR);
  float*     Mmax = (float*)(ws + OFF_MMAX);
  float*     Mmin = (float*)(ws + OFF_MMIN);
  float*     out  = (float*)d_out;

  hipLaunchKernelGGL(k_prep,  dim3(NQ/4), dim3(256), 0, stream, xyz, points, W0, b0, xyz4, Qb, Rb);
  hipLaunchKernelGGL(k_cast,  dim3(32),   dim3(256), 0, stream, W1, W2, W1h, W2h);
  hipLaunchKernelGGL(k_knn,   dim3(NQ/4), dim3(256), 0, stream, xyz4, idxb);
  hipLaunchKernelGGL(k_stats0,dim3(1024), dim3(256), 0, stream, Rb, Qb, idxb, p0);
  hipLaunchKernelGGL(k_fin,   dim3(1),    dim3(64),  0, stream, p0, 64, g0, beta0, par, 0);
  hipLaunchKernelGGL(k_l1,    dim3(1024), dim3(256), 0, stream, Rb, Qb, idxb, W1h, b1, par, p1);
  hipLaunchKernelGGL(k_fin,   dim3(1),    dim3(64),  0, stream, p1, 64, g1, beta1, par, 128);
  hipLaunchKernelGGL(k_l2,    dim3(1024), dim3(256), 0, stream, Rb, Qb, idxb, W1h, W2h, b1, b2, par, p2, Mmax, Mmin);
  hipLaunchKernelGGL(k_fin,   dim3(1),    dim3(128), 0, stream, p2, 128, g2, beta2, par, 256);
  hipLaunchKernelGGL(k_out,   dim3(out_size/256), dim3(256), 0, stream, Mmax, Mmin, par, out);
}

// Round 8
// 537.258 us; speedup vs baseline: 1.9357x; 1.0938x over previous
//
#include <hip/hip_runtime.h>

// ---------------------------------------------------------------------------
// PointNet++ set-abstraction block on MI355X.
// B=8, N=4096, K=32, D=64; out [B,N,128] fp32.
//  - layer0 linear decomposition: h0_pre = R[j] - Q[n]
//  - BN training-mode stats via per-block partials + finalize kernels
//  - layers 1/2 as fp16 MFMA (16x16x32) with fp32 accum
//  - max over K commutes with monotone BN affine: store max&min of h2 only
//  - kNN (R7, proven): chunked pair-insertion, tau bisect, readlane inserts
//  - R8: float4/half4 vectorized gather+stats+out (instruction-bound fix),
//    k_cast folded into k_prep.
// ---------------------------------------------------------------------------

using half4  = __attribute__((ext_vector_type(4))) _Float16;
using half8  = __attribute__((ext_vector_type(8))) _Float16;
using floatx4 = __attribute__((ext_vector_type(4))) float;

#define NB 8
#define NP 4096
#define NQ (NB*NP)          // 32768 points / queries
#define CNT_INV (1.0f/1048576.0f)   // 1/(B*N*K), exact power of two

// ---- workspace layout (bytes) ----
#define OFF_XYZ4  0ull
#define OFF_Q     (OFF_XYZ4 + (size_t)NQ*4*4)       // xyz4: x,y,z,|x|^2
#define OFF_R     (OFF_Q    + (size_t)NQ*64*4)
#define OFF_IDX   (OFF_R    + (size_t)NQ*64*4)
#define OFF_W1H   (OFF_IDX  + (size_t)NQ*32*4)
#define OFF_W2H   (OFF_W1H  + 4096*2)
#define OFF_P0    (OFF_W2H  + 8192*2)
#define OFF_P1    (OFF_P0   + (size_t)1024*128*4)
#define OFF_P2    (OFF_P1   + (size_t)1024*128*4)
#define OFF_PAR   (OFF_P2   + (size_t)1024*256*4)
#define OFF_MMAX  (OFF_PAR  + 512*4)
#define OFF_MMIN  (OFF_MMAX + (size_t)NQ*128*4)

// ---------------------------------------------------------------------------
// K0: per-point prep (+ fused W1/W2 fp16 cast in trailing blocks)
// ---------------------------------------------------------------------------
__global__ __launch_bounds__(256) void k_prep(
    const float* __restrict__ xyz, const float* __restrict__ points,
    const float* __restrict__ W0, const float* __restrict__ b0,
    const float* __restrict__ W1, const float* __restrict__ W2,
    float* __restrict__ xyz4, float* __restrict__ Q, float* __restrict__ R,
    _Float16* __restrict__ W1h, _Float16* __restrict__ W2h) {
  if (blockIdx.x >= NQ/4) {   // fused k_cast
    int t = (blockIdx.x - NQ/4)*256 + threadIdx.x;
    if (t < 4096) W1h[t] = (_Float16)W1[t];
    if (t < 8192) W2h[t] = (_Float16)W2[t];
    return;
  }
  __shared__ float w0s[64*67];
  for (int i = threadIdx.x; i < 64*67; i += 256) w0s[i] = W0[i];
  __syncthreads();
  int p = blockIdx.x*4 + (threadIdx.x >> 6);
  int o = threadIdx.x & 63;
  float x = xyz[p*3+0], y = xyz[p*3+1], z = xyz[p*3+2];
  const float* wr = w0s + o*67;
  float q = wr[0]*x + wr[1]*y + wr[2]*z;
  float r = b0[o] + q;
  const float4* pp4 = (const float4*)(points + (size_t)p*64);
  #pragma unroll
  for (int c4 = 0; c4 < 16; ++c4) {
    float4 pv = pp4[c4];
    r = fmaf(wr[3+4*c4+0], pv.x, r);
    r = fmaf(wr[3+4*c4+1], pv.y, r);
    r = fmaf(wr[3+4*c4+2], pv.z, r);
    r = fmaf(wr[3+4*c4+3], pv.w, r);
  }
  Q[(size_t)p*64 + o] = q;
  R[(size_t)p*64 + o] = r;
  if (o == 0) {
    float sq = fmaf(x,x, fmaf(y,y, z*z));
    xyz4[p*4+0]=x; xyz4[p*4+1]=y; xyz4[p*4+2]=z; xyz4[p*4+3]=sq;
  }
}

// ---------------------------------------------------------------------------
// K1: exact kNN (R7-proven; unchanged).
// ---------------------------------------------------------------------------
__device__ __forceinline__ unsigned fmap(float f) {
  unsigned u = __float_as_uint(f);
  return u ^ ((unsigned)((int)u >> 31) | 0x80000000u);
}

#define INSERT_ROUND(uu, jj)                                                  \
  {                                                                           \
    unsigned long long ball = __ballot((uu) <= utau && (uu) < thr);           \
    while (ball) {                                                            \
      int src = __ffsll(ball) - 1;                                            \
      ball &= ball - 1;                                                       \
      unsigned cu = (unsigned)__builtin_amdgcn_readlane((int)(uu), src);      \
      int cj = __builtin_amdgcn_readlane((jj), src);                          \
      if (cu < thr) {                                                         \
        unsigned long long m = __ballot(lane < 32 && ku < cu);                \
        int pos = __popcll(m);                                                \
        unsigned ku_up = __shfl_up(ku, 1);                                    \
        int jv_up = __shfl_up(jv, 1);                                         \
        if (lane < 32) {                                                      \
          if (lane > pos)      { ku = ku_up; jv = jv_up; }                    \
          else if (lane == pos){ ku = cu;    jv = cj;    }                    \
        }                                                                     \
        thr = (unsigned)__builtin_amdgcn_readlane((int)ku, 31);               \
      }                                                                       \
    }                                                                         \
  }

__global__ __launch_bounds__(256, 6) void k_knn(
    const float* __restrict__ xyz4, int* __restrict__ idxb) {
  const int lane = threadIdx.x & 63;
  const int w = threadIdx.x >> 6;
  const int qid = blockIdx.x * 4 + w;
  const int b = qid >> 12;
  const float4* xb = (const float4*)xyz4 + (size_t)b * NP;
  const float4 qv = xb[qid & (NP-1)];
  int* op = idxb + (size_t)qid * 32;

  float dvA[32];
  float mn = __uint_as_float(0x7F800000u);
  #pragma unroll
  for (int c = 0; c < 32; ++c) {
    float4 cd = xb[c*64 + lane];
    float dot = fmaf(qv.x, cd.x, fmaf(qv.y, cd.y, qv.z*cd.z));
    float d   = fmaf(-2.0f, dot, qv.w + cd.w);
    dvA[c] = d;
    mn = fminf(mn, d);
  }

  const unsigned mu = fmap(mn);
  unsigned lo = 0u, hi = 0xFFFFFFFFu;
  for (int it = 0; it < 32; ++it) {
    unsigned mid = lo + ((hi - lo) >> 1);
    int cnt = __popcll(__ballot(mu <= mid));
    if (cnt >= 32) hi = mid; else lo = mid + 1;
  }
  const unsigned utau = hi;

  unsigned ku = 0xFFFFFFFFu;
  int jv = 0;
  unsigned thr = 0xFFFFFFFFu;
  #pragma unroll
  for (int c = 0; c < 32; ++c) {
    unsigned u = fmap(dvA[c]);
    int j = c*64 + lane;
    INSERT_ROUND(u, j)
  }
  #pragma unroll 8
  for (int c = 32; c < 64; ++c) {
    float4 cd = xb[c*64 + lane];
    float dot = fmaf(qv.x, cd.x, fmaf(qv.y, cd.y, qv.z*cd.z));
    float d   = fmaf(-2.0f, dot, qv.w + cd.w);
    unsigned u = fmap(d);
    int j = c*64 + lane;
    INSERT_ROUND(u, j)
  }
  if (lane < 32) op[lane] = jv;
}

// ---------------------------------------------------------------------------
// K2: stats of h0_pre = R[j] - Q[n]; float4-vectorized.
// thread = (q_local 0..3, rg 0..3, seg 0..15); 1024 blocks x 32 queries.
// ---------------------------------------------------------------------------
__global__ __launch_bounds__(256) void k_stats0(
    const float* __restrict__ R, const float* __restrict__ Q,
    const int* __restrict__ idxb, float* __restrict__ p0) {
  const int q_local = threadIdx.x >> 6;
  const int rg  = (threadIdx.x >> 4) & 3;
  const int seg = threadIdx.x & 15;
  float4 s4 = {0.f,0.f,0.f,0.f}, ss4 = {0.f,0.f,0.f,0.f};
  for (int gi = 0; gi < 8; ++gi) {
    int qid = blockIdx.x*32 + gi*4 + q_local;
    const float* Rb = R + (size_t)(qid & ~4095)*64;
    const int* ix = idxb + (size_t)qid*32;
    float4 Q4 = ((const float4*)(Q + (size_t)qid*64))[seg];
    #pragma unroll
    for (int i = 0; i < 8; ++i) {
      int j = ix[rg + (i<<2)];
      float4 R4 = ((const float4*)(Rb + (size_t)j*64))[seg];
      float vx = R4.x - Q4.x, vy = R4.y - Q4.y, vz = R4.z - Q4.z, vw = R4.w - Q4.w;
      s4.x += vx; s4.y += vy; s4.z += vz; s4.w += vw;
      ss4.x = fmaf(vx,vx,ss4.x); ss4.y = fmaf(vy,vy,ss4.y);
      ss4.z = fmaf(vz,vz,ss4.z); ss4.w = fmaf(vw,vw,ss4.w);
    }
  }
  __shared__ float4 redS[256], redSS[256];
  redS[threadIdx.x] = s4; redSS[threadIdx.x] = ss4;
  __syncthreads();
  if (threadIdx.x < 16) {
    int sg = threadIdx.x;
    float4 S = {0.f,0.f,0.f,0.f}, SS = {0.f,0.f,0.f,0.f};
    #pragma unroll
    for (int m = 0; m < 16; ++m) {
      float4 a = redS[sg + 16*m], c = redSS[sg + 16*m];
      S.x+=a.x; S.y+=a.y; S.z+=a.z; S.w+=a.w;
      SS.x+=c.x; SS.y+=c.y; SS.z+=c.z; SS.w+=c.w;
    }
    ((float4*)(p0 + blockIdx.x*128))[sg]      = S;
    ((float4*)(p0 + blockIdx.x*128 + 64))[sg] = SS;
  }
}

// ---------------------------------------------------------------------------
// K3: finalize BN stats -> affine params (scale, shift) at par[poff..]
// ---------------------------------------------------------------------------
__global__ void k_fin(const float* __restrict__ part, int C,
                      const float* __restrict__ g, const float* __restrict__ beta,
                      float* __restrict__ par, int poff) {
  int o = threadIdx.x;
  float S = 0.f, SS = 0.f;
  for (int s = 0; s < 1024; ++s) {
    S  += part[s*2*C + o];
    SS += part[s*2*C + C + o];
  }
  float mu  = S * CNT_INV;
  float var = SS * CNT_INV - mu*mu;
  float sc  = g[o] * rsqrtf(var + 1e-5f);
  par[poff + o]     = sc;
  par[poff + C + o] = beta[o] - mu*sc;
}

// ---------------------------------------------------------------------------
// Phase-A helper macro: vectorized x1 build (float4 gather -> half4 LDS)
// thread = (q_local, rg, seg); writes rows q_local*32 + rg+4i, chans seg*4..+3
// ---------------------------------------------------------------------------
#define BUILD_X1(q0)                                                          \
  {                                                                           \
    int qid = (q0) + aql;                                                     \
    const float* Rb = R + (size_t)(qid & ~4095)*64;                           \
    const int* ix = idxb + (size_t)qid*32;                                    \
    float4 Q4 = ((const float4*)(Q + (size_t)qid*64))[aseg];                  \
    float qx = fmaf(-Q4.x, asc.x, ash.x);                                     \
    float qy = fmaf(-Q4.y, asc.y, ash.y);                                     \
    float qz = fmaf(-Q4.z, asc.z, ash.z);                                     \
    float qw = fmaf(-Q4.w, asc.w, ash.w);                                     \
    _Pragma("unroll")                                                         \
    for (int i = 0; i < 8; ++i) {                                             \
      int k = arg + (i<<2);                                                   \
      int j = ix[k];                                                          \
      float4 R4 = ((const float4*)(Rb + (size_t)j*64))[aseg];                 \
      float v0 = fmaxf(fmaf(R4.x, asc.x, qx), 0.f);                           \
      float v1 = fmaxf(fmaf(R4.y, asc.y, qy), 0.f);                           \
      float v2 = fmaxf(fmaf(R4.z, asc.z, qz), 0.f);                           \
      float v3 = fmaxf(fmaf(R4.w, asc.w, qw), 0.f);                           \
      half4 hv = {(_Float16)v0, (_Float16)v1, (_Float16)v2, (_Float16)v3};    \
      *(half4*)(x1 + (aql*32 + k)*72 + aseg*4) = hv;                          \
    }                                                                         \
  }

// ---------------------------------------------------------------------------
// K4: layer1 via fp16 MFMA; emit stats1 partials.
// ---------------------------------------------------------------------------
__global__ __launch_bounds__(256) void k_l1(
    const float* __restrict__ R, const float* __restrict__ Q,
    const int* __restrict__ idxb, const _Float16* __restrict__ W1h,
    const float* __restrict__ b1, const float* __restrict__ par,
    float* __restrict__ p1) {
  __shared__ __align__(16) _Float16 x1[128*72];
  int o = threadIdx.x & 63, wg = threadIdx.x >> 6;
  int m16 = o & 15, quad = o >> 4;
  // phase-A mapping
  const int aql = threadIdx.x >> 6;
  const int arg = (threadIdx.x >> 4) & 3;
  const int aseg = threadIdx.x & 15;
  const float4 asc = ((const float4*)par)[aseg];
  const float4 ash = ((const float4*)(par+64))[aseg];
  // phase-B fragments
  int col = wg*16 + m16;
  half8 bf0 = *(const half8*)(W1h + col*64 + quad*8);
  half8 bf1 = *(const half8*)(W1h + col*64 + 32 + quad*8);
  float b1c = b1[col];
  float s = 0.f, ss = 0.f;

  for (int gi = 0; gi < 8; ++gi) {
    int q0 = (blockIdx.x*8 + gi) * 4;
    BUILD_X1(q0)
    __syncthreads();
    #pragma unroll
    for (int rt = 0; rt < 8; ++rt) {
      const _Float16* ap = x1 + (rt*16 + m16)*72 + quad*8;
      half8 a0 = *(const half8*)(ap);
      half8 a1 = *(const half8*)(ap + 32);
      floatx4 acc = {0.f,0.f,0.f,0.f};
      acc = __builtin_amdgcn_mfma_f32_16x16x32_f16(a0, bf0, acc, 0,0,0);
      acc = __builtin_amdgcn_mfma_f32_16x16x32_f16(a1, bf1, acc, 0,0,0);
      #pragma unroll
      for (int rg = 0; rg < 4; ++rg) {
        float h = acc[rg] + b1c;
        s += h; ss = fmaf(h, h, ss);
      }
    }
    __syncthreads();
  }
  s  += __shfl_xor(s, 16);  s  += __shfl_xor(s, 32);
  ss += __shfl_xor(ss, 16); ss += __shfl_xor(ss, 32);
  if (quad == 0) {
    p1[blockIdx.x*128 + col]      = s;
    p1[blockIdx.x*128 + 64 + col] = ss;
  }
}

// ---------------------------------------------------------------------------
// K6: layer1 (recompute) -> bn1+relu -> layer2 MFMA -> stats2 + max/min
// ---------------------------------------------------------------------------
__global__ __launch_bounds__(256) void k_l2(
    const float* __restrict__ R, const float* __restrict__ Q,
    const int* __restrict__ idxb, const _Float16* __restrict__ W1h,
    const _Float16* __restrict__ W2h, const float* __restrict__ b1,
    const float* __restrict__ b2, const float* __restrict__ par,
    float* __restrict__ p2, float* __restrict__ Mmax, float* __restrict__ Mmin) {
  __shared__ __align__(16) _Float16 x1[128*72];
  __shared__ __align__(16) _Float16 x2[128*72];
  int o = threadIdx.x & 63, wg = threadIdx.x >> 6;
  int m16 = o & 15, quad = o >> 4;
  const int aql = threadIdx.x >> 6;
  const int arg = (threadIdx.x >> 4) & 3;
  const int aseg = threadIdx.x & 15;
  const float4 asc = ((const float4*)par)[aseg];
  const float4 ash = ((const float4*)(par+64))[aseg];
  int col1 = wg*16 + m16;
  float sc1 = par[128 + col1], sh1 = par[192 + col1];
  half8 b1f0 = *(const half8*)(W1h + col1*64 + quad*8);
  half8 b1f1 = *(const half8*)(W1h + col1*64 + 32 + quad*8);
  float b1c = b1[col1];
  int colA = wg*16 + m16, colB = 64 + wg*16 + m16;
  half8 b2A0 = *(const half8*)(W2h + colA*64 + quad*8);
  half8 b2A1 = *(const half8*)(W2h + colA*64 + 32 + quad*8);
  half8 b2B0 = *(const half8*)(W2h + colB*64 + quad*8);
  half8 b2B1 = *(const half8*)(W2h + colB*64 + 32 + quad*8);
  float b2a = b2[colA], b2b = b2[colB];
  float sA=0.f, ssA=0.f, sB=0.f, ssB=0.f;

  for (int gi = 0; gi < 8; ++gi) {
    int q0 = (blockIdx.x*8 + gi) * 4;
    BUILD_X1(q0)
    __syncthreads();
    #pragma unroll
    for (int rt = 0; rt < 8; ++rt) {
      const _Float16* ap = x1 + (rt*16 + m16)*72 + quad*8;
      half8 a0 = *(const half8*)(ap);
      half8 a1 = *(const half8*)(ap + 32);
      floatx4 acc = {0.f,0.f,0.f,0.f};
      acc = __builtin_amdgcn_mfma_f32_16x16x32_f16(a0, b1f0, acc, 0,0,0);
      acc = __builtin_amdgcn_mfma_f32_16x16x32_f16(a1, b1f1, acc, 0,0,0);
      #pragma unroll
      for (int rg = 0; rg < 4; ++rg) {
        float h = acc[rg] + b1c;
        float v = fmaxf(fmaf(h, sc1, sh1), 0.f);
        x2[(rt*16 + quad*4 + rg)*72 + col1] = (_Float16)v;
      }
    }
    __syncthreads();
    float mxA=0.f, mnA=0.f, mxB=0.f, mnB=0.f;
    #pragma unroll
    for (int rt = 0; rt < 8; ++rt) {
      const _Float16* ap = x2 + (rt*16 + m16)*72 + quad*8;
      half8 a0 = *(const half8*)(ap);
      half8 a1 = *(const half8*)(ap + 32);
      floatx4 accA = {0.f,0.f,0.f,0.f}, accB = {0.f,0.f,0.f,0.f};
      accA = __builtin_amdgcn_mfma_f32_16x16x32_f16(a0, b2A0, accA, 0,0,0);
      accA = __builtin_amdgcn_mfma_f32_16x16x32_f16(a1, b2A1, accA, 0,0,0);
      accB = __builtin_amdgcn_mfma_f32_16x16x32_f16(a0, b2B0, accB, 0,0,0);
      accB = __builtin_amdgcn_mfma_f32_16x16x32_f16(a1, b2B1, accB, 0,0,0);
      float hA0 = accA[0]+b2a, hA1 = accA[1]+b2a, hA2 = accA[2]+b2a, hA3 = accA[3]+b2a;
      float hB0 = accB[0]+b2b, hB1 = accB[1]+b2b, hB2 = accB[2]+b2b, hB3 = accB[3]+b2b;
      sA += hA0+hA1+hA2+hA3;
      ssA = fmaf(hA0,hA0, fmaf(hA1,hA1, fmaf(hA2,hA2, fmaf(hA3,hA3, ssA))));
      sB += hB0+hB1+hB2+hB3;
      ssB = fmaf(hB0,hB0, fmaf(hB1,hB1, fmaf(hB2,hB2, fmaf(hB3,hB3, ssB))));
      float m4A = fmaxf(fmaxf(hA0,hA1), fmaxf(hA2,hA3));
      float n4A = fminf(fminf(hA0,hA1), fminf(hA2,hA3));
      float m4B = fmaxf(fmaxf(hB0,hB1), fmaxf(hB2,hB3));
      float n4B = fminf(fminf(hB0,hB1), fminf(hB2,hB3));
      if ((rt & 1) == 0) { mxA=m4A; mnA=n4A; mxB=m4B; mnB=n4B; }
      else {
        mxA=fmaxf(mxA,m4A); mnA=fminf(mnA,n4A);
        mxB=fmaxf(mxB,m4B); mnB=fminf(mnB,n4B);
        mxA=fmaxf(mxA,__shfl_xor(mxA,16)); mxA=fmaxf(mxA,__shfl_xor(mxA,32));
        mnA=fminf(mnA,__shfl_xor(mnA,16)); mnA=fminf(mnA,__shfl_xor(mnA,32));
        mxB=fmaxf(mxB,__shfl_xor(mxB,16)); mxB=fmaxf(mxB,__shfl_xor(mxB,32));
        mnB=fminf(mnB,__shfl_xor(mnB,16)); mnB=fminf(mnB,__shfl_xor(mnB,32));
        if (quad == 0) {
          int qid = q0 + (rt >> 1);
          Mmax[(size_t)qid*128 + colA] = mxA;  Mmin[(size_t)qid*128 + colA] = mnA;
          Mmax[(size_t)qid*128 + colB] = mxB;  Mmin[(size_t)qid*128 + colB] = mnB;
        }
      }
    }
    __syncthreads();
  }
  sA += __shfl_xor(sA,16); sA += __shfl_xor(sA,32);
  ssA += __shfl_xor(ssA,16); ssA += __shfl_xor(ssA,32);
  sB += __shfl_xor(sB,16); sB += __shfl_xor(sB,32);
  ssB += __shfl_xor(ssB,16); ssB += __shfl_xor(ssB,32);
  if (quad == 0) {
    p2[blockIdx.x*256 + colA]        = sA;
    p2[blockIdx.x*256 + 128 + colA]  = ssA;
    p2[blockIdx.x*256 + colB]        = sB;
    p2[blockIdx.x*256 + 128 + colB]  = ssB;
  }
}

// ---------------------------------------------------------------------------
// K7: out = relu(affine2(max-or-min)); float4.
// ---------------------------------------------------------------------------
__global__ __launch_bounds__(256) void k_out(
    const float* __restrict__ Mmax, const float* __restrict__ Mmin,
    const float* __restrict__ par, float* __restrict__ out) {
  int t = blockIdx.x*256 + threadIdx.x;
  int seg = t & 31;                       // 128 channels / 4
  float4 sc = ((const float4*)(par+256))[seg];
  float4 sh = ((const float4*)(par+384))[seg];
  float4 mx = ((const float4*)Mmax)[t];
  float4 mn = ((const float4*)Mmin)[t];
  float4 o;
  o.x = fmaxf(fmaf(sc.x >= 0.f ? mx.x : mn.x, sc.x, sh.x), 0.f);
  o.y = fmaxf(fmaf(sc.y >= 0.f ? mx.y : mn.y, sc.y, sh.y), 0.f);
  o.z = fmaxf(fmaf(sc.z >= 0.f ? mx.z : mn.z, sc.z, sh.z), 0.f);
  o.w = fmaxf(fmaf(sc.w >= 0.f ? mx.w : mn.w, sc.w, sh.w), 0.f);
  ((float4*)out)[t] = o;
}

// ---------------------------------------------------------------------------
extern "C" void kernel_launch(void* const* d_in, const int* in_sizes, int n_in,
                              void* d_out, int out_size, void* d_ws, size_t ws_size,
                              hipStream_t stream) {
  const float* xyz    = (const float*)d_in[0];
  const float* points = (const float*)d_in[1];
  const float* W0     = (const float*)d_in[2];
  const float* b0     = (const float*)d_in[3];
  const float* g0     = (const float*)d_in[4];
  const float* beta0  = (const float*)d_in[5];
  const float* W1     = (const float*)d_in[6];
  const float* b1     = (const float*)d_in[7];
  const float* g1     = (const float*)d_in[8];
  const float* beta1  = (const float*)d_in[9];
  const float* W2     = (const float*)d_in[10];
  const float* b2     = (const float*)d_in[11];
  const float* g2     = (const float*)d_in[12];
  const float* beta2  = (const float*)d_in[13];

  char* ws = (char*)d_ws;
  float*     xyz4 = (float*)(ws + OFF_XYZ4);
  float*     Qb   = (float*)(ws + OFF_Q);
  float*     Rb   = (float*)(ws + OFF_R);
  int*       idxb = (int*)  (ws + OFF_IDX);
  _Float16*  W1h  = (_Float16*)(ws + OFF_W1H);
  _Float16*  W2h  = (_Float16*)(ws + OFF_W2H);
  float*     p0   = (float*)(ws + OFF_P0);
  float*     p1   = (float*)(ws + OFF_P1);
  float*     p2   = (float*)(ws + OFF_P2);
  float*     par  = (float*)(ws + OFF_PAR);
  float*     Mmax = (float*)(ws + OFF_MMAX);
  float*     Mmin = (float*)(ws + OFF_MMIN);
  float*     out  = (float*)d_out;

  hipLaunchKernelGGL(k_prep,  dim3(NQ/4 + 32), dim3(256), 0, stream,
                     xyz, points, W0, b0, W1, W2, xyz4, Qb, Rb, W1h, W2h);
  hipLaunchKernelGGL(k_knn,   dim3(NQ/4), dim3(256), 0, stream, xyz4, idxb);
  hipLaunchKernelGGL(k_stats0,dim3(1024), dim3(256), 0, stream, Rb, Qb, idxb, p0);
  hipLaunchKernelGGL(k_fin,   dim3(1),    dim3(64),  0, stream, p0, 64, g0, beta0, par, 0);
  hipLaunchKernelGGL(k_l1,    dim3(1024), dim3(256), 0, stream, Rb, Qb, idxb, W1h, b1, par, p1);
  hipLaunchKernelGGL(k_fin,   dim3(1),    dim3(64),  0, stream, p1, 64, g1, beta1, par, 128);
  hipLaunchKernelGGL(k_l2,    dim3(1024), dim3(256), 0, stream, Rb, Qb, idxb, W1h, W2h, b1, b2, par, p2, Mmax, Mmin);
  hipLaunchKernelGGL(k_fin,   dim3(1),    dim3(128), 0, stream, p2, 128, g2, beta2, par, 256);
  hipLaunchKernelGGL(k_out,   dim3(out_size/1024), dim3(256), 0, stream, Mmax, Mmin, par, out);
}